// Round 5
// baseline (407.287 us; speedup 1.0000x reference)
//
#include <hip/hip_runtime.h>
#include <hip/hip_bf16.h>
#include <stdint.h>

#define NN 4096
#define NF 128
#define NB 4
#define KC 64                // k-floats staged per stage
#define NSTAGE (NN / KC)     // 64

typedef __attribute__((ext_vector_type(4))) float  floatx4;
typedef __attribute__((ext_vector_type(8))) __bf16 bf16x8;

// async global->LDS, 16B per lane; LDS dest = uniform base + lane*16
__device__ __forceinline__ void load_lds_16(const float* g, float* l) {
    __builtin_amdgcn_global_load_lds(
        (const __attribute__((address_space(1))) uint32_t*)g,
        (__attribute__((address_space(3))) uint32_t*)l, 16, 0, 0);
}

// ---------------------------------------------------------------------------
// Prep: Xpack[b][kc][f][k8] = bf16(X[b][kc*32+k8][f])  via LDS transpose.
//       wpack[kc2][n][k8]   = bf16(w[kc2*32+k8][n])
// ---------------------------------------------------------------------------
__global__ __launch_bounds__(256) void prep_kernel(const float* __restrict__ X,
                                                   const float* __restrict__ w,
                                                   __bf16* __restrict__ Xpack,
                                                   __bf16* __restrict__ wpack) {
    __shared__ float Xs[32][129];
    const int tid = threadIdx.x;
    const int bx  = blockIdx.x;
    if (bx == 512) {  // wpack: tiny
        for (int p = tid; p < 512; p += 256) {
            int kc = p >> 7, n = p & 127;
#pragma unroll
            for (int k8 = 0; k8 < 32; k8 += 8) {
                bf16x8 v;
#pragma unroll
                for (int j = 0; j < 8; j++)
                    v[j] = (__bf16)w[(size_t)(kc * 32 + k8 + j) * NF + n];
                *(bf16x8*)(wpack + ((size_t)(kc * 128 + n)) * 32 + k8) = v;
            }
        }
        return;
    }
    const int b  = bx >> 7;
    const int kc = bx & 127;
    const float* Xt = X + ((size_t)b * NN + (size_t)kc * 32) * NF;
#pragma unroll
    for (int j = 0; j < 16; j++) {
        int i = tid + j * 256;
        Xs[i >> 7][i & 127] = Xt[i];
    }
    __syncthreads();
    const int f  = tid >> 1;
    const int kh = (tid & 1) * 16;
    bf16x8 v0, v1;
#pragma unroll
    for (int j = 0; j < 8; j++) v0[j] = (__bf16)Xs[kh + j][f];
#pragma unroll
    for (int j = 0; j < 8; j++) v1[j] = (__bf16)Xs[kh + 8 + j][f];
    __bf16* op = Xpack + (((size_t)b * 128 + kc) * 128 + f) * 32 + kh;
    *(bf16x8*)op = v0;
    *(bf16x8*)(op + 8) = v1;
}

// ---------------------------------------------------------------------------
// Main: block = 64 rows x 128 cols (256 blocks -> 1/CU, 8 waves of 512 thr).
// Restructured K-loop: 3-deep global_load_lds pipeline (KC=64, 64 stages),
// raw s_barrier + explicit vmcnt(2) (no implicit full drain), B loads issued
// BEFORE next DMA so in-order vmcnt never forces prefetch completion.
// LDS chunk layout: 1KB DMA chunk = 4 rows x 256B, +16B pad -> frag
// ds_read_b128 is exactly 8 words/bank (conflict-free). Us aliased onto At.
// ---------------------------------------------------------------------------
__global__ __launch_bounds__(512, 2) void main_kernel(const float* __restrict__ A,
                                                      const float* __restrict__ X,
                                                      const __bf16* __restrict__ Xpack,
                                                      const __bf16* __restrict__ wpack,
                                                      float* __restrict__ out) {
    __shared__ float At[3][16][260];  // chunk g = rows 4g..4g+3, 64 k-floats each
    __bf16(*Us)[136] = (__bf16(*)[136]) & At[0][0][0];  // reused after K-loop

    const int tid  = threadIdx.x;
    const int wv   = tid >> 6;
    const int lane = tid & 63;
    const int lm   = lane & 15;
    const int quad = lane >> 4;
    const int rg   = wv & 1;
    const int cg   = wv >> 1;

    const int b  = blockIdx.x >> 6;        // 256 blocks = 4 b * 64 m-tiles
    const int m0 = (blockIdx.x & 63) << 6;

    // DMA: wave stages chunks g = wv*2, wv*2+1 ; chunk = rows 4g..4g+3.
    // lane L -> row 4g + (L>>4), float col (L&15)*4 (one 1KB contiguous write)
    const float* Asrc[2];
#pragma unroll
    for (int j = 0; j < 2; j++)
        Asrc[j] = A + ((size_t)b * NN + m0 + 4 * (wv * 2 + j) + (lane >> 4)) * NN
                    + (lane & 15) * 4;

    const __bf16* Bbase = Xpack + ((size_t)b * 128 * NF + (cg * 32 + lm)) * 32 + quad * 8;

    floatx4 acc[2][2];
#pragma unroll
    for (int i = 0; i < 2; i++)
#pragma unroll
        for (int j = 0; j < 2; j++) acc[i][j] = (floatx4){0.f, 0.f, 0.f, 0.f};
    float ds0 = 0.f, ds1 = 0.f;

    const int r0 = rg * 32 + lm;
    const int r1 = r0 + 16;
    const int c0 = r0 >> 2, o0 = (r0 & 3) * 64 + quad * 8;
    const int c1 = r1 >> 2, o1 = (r1 & 3) * 64 + quad * 8;

    // prologue: DMA stages 0,1 -> bufs 0,1
#pragma unroll
    for (int j = 0; j < 2; j++) load_lds_16(Asrc[j], &At[0][wv * 2 + j][0]);
#pragma unroll
    for (int j = 0; j < 2; j++) load_lds_16(Asrc[j] + KC, &At[1][wv * 2 + j][0]);

    auto stage = [&](int s, bool last) {
        if (last) __builtin_amdgcn_s_waitcnt(0x0f70);  // vmcnt(0)
        else      __builtin_amdgcn_s_waitcnt(0x0f72);  // vmcnt(2): my DMA_s done
        __builtin_amdgcn_s_barrier();                  // raw: no implicit drain
        __builtin_amdgcn_sched_barrier(0);
        const int buf = s % 3;
        // B loads FIRST (so their waits leave the prefetch DMAs outstanding)
        bf16x8 bfr[2][2];
        const __bf16* Bs = Bbase + (size_t)(2 * s) * 4096;
#pragma unroll
        for (int kk = 0; kk < 2; kk++) {
            bfr[kk][0] = *(const bf16x8*)(Bs + (size_t)kk * 4096);
            bfr[kk][1] = *(const bf16x8*)(Bs + (size_t)kk * 4096 + 512);
        }
        __builtin_amdgcn_sched_barrier(0);
        if (s + 2 < NSTAGE) {
            const int wbuf = (s + 2) % 3;
#pragma unroll
            for (int j = 0; j < 2; j++)
                load_lds_16(Asrc[j] + (size_t)(s + 2) * KC, &At[wbuf][wv * 2 + j][0]);
        }
        __builtin_amdgcn_sched_barrier(0);
#pragma unroll
        for (int kk = 0; kk < 2; kk++) {
            floatx4 a00 = *(const floatx4*)&At[buf][c0][o0 + kk * 32];
            floatx4 a01 = *(const floatx4*)&At[buf][c0][o0 + kk * 32 + 4];
            floatx4 a10 = *(const floatx4*)&At[buf][c1][o1 + kk * 32];
            floatx4 a11 = *(const floatx4*)&At[buf][c1][o1 + kk * 32 + 4];
            ds0 += a00[0] + a00[1] + a00[2] + a00[3] + a01[0] + a01[1] + a01[2] + a01[3];
            ds1 += a10[0] + a10[1] + a10[2] + a10[3] + a11[0] + a11[1] + a11[2] + a11[3];
            bf16x8 af0, af1;
#pragma unroll
            for (int i = 0; i < 4; i++) { af0[i] = (__bf16)a00[i]; af0[4 + i] = (__bf16)a01[i]; }
#pragma unroll
            for (int i = 0; i < 4; i++) { af1[i] = (__bf16)a10[i]; af1[4 + i] = (__bf16)a11[i]; }
            acc[0][0] = __builtin_amdgcn_mfma_f32_16x16x32_bf16(af0, bfr[kk][0], acc[0][0], 0, 0, 0);
            acc[0][1] = __builtin_amdgcn_mfma_f32_16x16x32_bf16(af0, bfr[kk][1], acc[0][1], 0, 0, 0);
            acc[1][0] = __builtin_amdgcn_mfma_f32_16x16x32_bf16(af1, bfr[kk][0], acc[1][0], 0, 0, 0);
            acc[1][1] = __builtin_amdgcn_mfma_f32_16x16x32_bf16(af1, bfr[kk][1], acc[1][1], 0, 0, 0);
        }
    };

    for (int s = 0; s < NSTAGE - 1; s++) stage(s, false);
    stage(NSTAGE - 1, true);

    // full row-sums: combine the 4 quad k-phases
    ds0 += __shfl_xor(ds0, 16, 64); ds0 += __shfl_xor(ds0, 32, 64);
    ds1 += __shfl_xor(ds1, 16, 64); ds1 += __shfl_xor(ds1, 32, 64);
    float deg0[4], deg1[4];
#pragma unroll
    for (int i = 0; i < 4; i++) {
        deg0[i] = __shfl(ds0, quad * 4 + i, 64) + 1.0f;
        deg1[i] = __shfl(ds1, quad * 4 + i, 64) + 1.0f;
    }

    // preload w B-frags (L2-hot)
    bf16x8 wf[4][2];
#pragma unroll
    for (int kc2 = 0; kc2 < 4; kc2++)
#pragma unroll
        for (int nt = 0; nt < 2; nt++)
            wf[kc2][nt] = *(const bf16x8*)(wpack +
                ((size_t)(kc2 * 128 + cg * 32 + nt * 16 + lm)) * 32 + quad * 8);

    __syncthreads();  // all At reads done before Us (aliased) writes

    // u = (acc + X)/deg -> Us (bf16)
    const float* Xb = X + ((size_t)b * NN + m0) * NF;
#pragma unroll
    for (int sub = 0; sub < 2; sub++) {
#pragma unroll
        for (int nt = 0; nt < 2; nt++) {
            int col = cg * 32 + nt * 16 + lm;
#pragma unroll
            for (int i = 0; i < 4; i++) {
                int r = rg * 32 + sub * 16 + quad * 4 + i;  // C-layout row
                float d = sub ? deg1[i] : deg0[i];
                float u = (acc[sub][nt][i] + Xb[(size_t)r * NF + col]) / d;
                Us[r][col] = (__bf16)u;
            }
        }
    }
    __syncthreads();

    // z = u @ w (K=128); wave: its 2 row-subtiles x its 32 cols
    float* ob = out + ((size_t)b * NN + m0) * NF;
#pragma unroll
    for (int sub = 0; sub < 2; sub++) {
        int rm = rg * 32 + sub * 16;
        floatx4 z0 = {0.f, 0.f, 0.f, 0.f};
        floatx4 z1 = {0.f, 0.f, 0.f, 0.f};
#pragma unroll
        for (int kc2 = 0; kc2 < 4; kc2++) {
            bf16x8 ua = *(const bf16x8*)&Us[rm + lm][kc2 * 32 + quad * 8];
            z0 = __builtin_amdgcn_mfma_f32_16x16x32_bf16(ua, wf[kc2][0], z0, 0, 0, 0);
            z1 = __builtin_amdgcn_mfma_f32_16x16x32_bf16(ua, wf[kc2][1], z1, 0, 0, 0);
        }
#pragma unroll
        for (int nt = 0; nt < 2; nt++) {
            int col = cg * 32 + nt * 16 + lm;
            floatx4 zv = nt ? z1 : z0;
#pragma unroll
            for (int i = 0; i < 4; i++) {
                int r = rm + quad * 4 + i;
                float v = zv[i];
                ob[(size_t)r * NF + col] = v > 0.f ? v : 0.f;
            }
        }
    }
}

extern "C" void kernel_launch(void* const* d_in, const int* in_sizes, int n_in,
                              void* d_out, int out_size, void* d_ws, size_t ws_size,
                              hipStream_t stream) {
    const float* A = (const float*)d_in[0];  // [4,4096,4096]
    const float* X = (const float*)d_in[1];  // [4,4096,128]
    const float* w = (const float*)d_in[2];  // [128,128]
    float* out = (float*)d_out;              // [4,4096,128]

    __bf16* Xpack = (__bf16*)d_ws;                 // 4 MB
    __bf16* wpack = Xpack + (size_t)NB * NF * NN;  // +32 KB

    prep_kernel<<<513, 256, 0, stream>>>(X, w, Xpack, wpack);
    main_kernel<<<256, 512, 0, stream>>>(A, X, Xpack, wpack, out);
}